// Round 4
// baseline (278.517 us; speedup 1.0000x reference)
//
#include <hip/hip_runtime.h>

// Problem constants (fixed by setup_inputs: (2, 64, 320, 320), stoken 16x16)
#define KB   2
#define KC   64
#define KH   320
#define KW   320
#define KSH  16
#define KSW  16
#define KNSH 20
#define KNSW 20
#define KNS  400           // KNSH*KNSW
#define KN   102400        // KH*KW

typedef float float4v __attribute__((ext_vector_type(4)));

// ---------------------------------------------------------------------------
// Kernel A: spix0 = per-block mean of pixel features.
__global__ __launch_bounds__(320) void block_mean_kernel(
    const float* __restrict__ pf, float* __restrict__ spix) {
  int wg = blockIdx.x;
  int rb = wg % KNSH;
  int c  = (wg / KNSH) % KC;
  int b  = wg / (KNSH * KC);
  int t  = threadIdx.x;  // 0..319

  const float* row0 = pf + ((size_t)(b * KC + c) * KH + rb * KSH) * KW;
  float acc = 0.f;
#pragma unroll
  for (int i = 0; i < KSH; ++i) acc += row0[i * KW + t];

#pragma unroll
  for (int off = 8; off > 0; off >>= 1) acc += __shfl_down(acc, off, 16);

  if ((t & 15) == 0)
    spix[(b * KC + c) * KNS + rb * KNSW + (t >> 4)] = acc * (1.0f / (KSH * KSW));
}

// ---------------------------------------------------------------------------
// Kernel B: per-pixel 9-candidate distances + masked softmax -> aff (B, 9, N).
__global__ __launch_bounds__(256) void dist_aff_kernel(
    const float* __restrict__ pf, const float* __restrict__ spix,
    float* __restrict__ aff) {
  __shared__ float scand[9][KC];

  int wg = blockIdx.x;
  int s  = wg % KNS;
  int b  = wg / KNS;
  int sr = s / KNSW, sc = s % KNSW;
  int t  = threadIdx.x;

  for (int idx = t; idx < 9 * KC; idx += 256) {
    int k = idx >> 6, c = idx & 63;
    int rr = sr + k / 3 - 1, cc = sc + k % 3 - 1;
    float v = 0.f;
    if (rr >= 0 && rr < KNSH && cc >= 0 && cc < KNSW)
      v = spix[(b * KC + c) * KNS + rr * KNSW + cc];
    scand[k][c] = v;
  }
  __syncthreads();

  int i = t >> 4, j = t & 15;
  int p = (sr * KSH + i) * KW + sc * KSW + j;
  const float* pfb = pf + (size_t)b * KC * KN + p;

  float d[9];
#pragma unroll
  for (int k = 0; k < 9; ++k) d[k] = 0.f;

  for (int c = 0; c < KC; ++c) {
    float x = pfb[(size_t)c * KN];
#pragma unroll
    for (int k = 0; k < 9; ++k) {
      float df = x - scand[k][c];
      d[k] = fmaf(df, df, d[k]);
    }
  }

  float m = 3.4e38f;
#pragma unroll
  for (int k = 0; k < 9; ++k) {
    int rr = sr + k / 3 - 1, cc = sc + k % 3 - 1;
    bool valid = (rr >= 0 && rr < KNSH && cc >= 0 && cc < KNSW);
    if (valid) m = fminf(m, d[k]);
  }
  float e[9];
  float sum = 0.f;
#pragma unroll
  for (int k = 0; k < 9; ++k) {
    int rr = sr + k / 3 - 1, cc = sc + k % 3 - 1;
    bool valid = (rr >= 0 && rr < KNSH && cc >= 0 && cc < KNSW);
    e[k] = valid ? __expf(m - d[k]) : 0.f;
    sum += e[k];
  }
  float inv = 1.0f / sum;
#pragma unroll
  for (int k = 0; k < 9; ++k)
    aff[((size_t)b * 9 + k) * KN + p] = e[k] * inv;
}

// ---------------------------------------------------------------------------
// Kernel C v3: spix1[b,c,s] = (sum_p aff*pf) / (sum_p aff + 1e-16), gather.
// One wg per (b,s), 256 threads = 4 waves; wave w owns channels 16w..16w+15.
// k-loop OUTERMOST (not unrolled): only 1 aff float4 + 1 pf float4 live at a
// time with 16 scalar accumulators -> ~90 VGPR, no spill (v2 forced a 16x
// unroll with 9 float4 loads per iter -> spill suspect).
__global__ __launch_bounds__(256) void update_spix_kernel(
    const float* __restrict__ pf, const float* __restrict__ aff,
    float* __restrict__ spix1) {
  __shared__ __align__(16) float aff_s[9][256];
  __shared__ float red_s[4];
  __shared__ float invden_s;

  int wg = blockIdx.x;
  int s  = wg % KNS;
  int b  = wg / KNS;
  int sr = s / KNSW, sc = s % KNSW;
  int t  = threadIdx.x;

  // stage aff (invalid neighbors -> 0) and accumulate denominator
  int ti = t >> 4, tj = t & 15;
  float psum = 0.f;
#pragma unroll
  for (int k = 0; k < 9; ++k) {
    int rr = sr + k / 3 - 1, cc = sc + k % 3 - 1;
    float a = 0.f;
    if (rr >= 0 && rr < KNSH && cc >= 0 && cc < KNSW) {
      int p = (rr * KSH + ti) * KW + cc * KSW + tj;
      a = aff[((size_t)b * 9 + (8 - k)) * KN + p];
    }
    aff_s[k][t] = a;
    psum += a;
  }
#pragma unroll
  for (int off = 32; off > 0; off >>= 1) psum += __shfl_down(psum, off, 64);
  if ((t & 63) == 0) red_s[t >> 6] = psum;
  __syncthreads();
  if (t == 0) invden_s = 1.0f / (red_s[0] + red_s[1] + red_s[2] + red_s[3] + 1e-16f);
  __syncthreads();
  float inv_den = invden_s;

  // clamped block bases (aff_s==0 masks invalid contributions)
  int pbase[9];
#pragma unroll
  for (int k = 0; k < 9; ++k) {
    int rr = min(max(sr + k / 3 - 1, 0), KNSH - 1);
    int cc = min(max(sc + k % 3 - 1, 0), KNSW - 1);
    pbase[k] = (rr * KSH) * KW + cc * KSW;
  }

  int w = t >> 6, l = t & 63;
  int li = l >> 2, lj4 = (l & 3) * 4;
  const float* pfb = pf + ((size_t)b * KC + w * 16) * KN;

  float acc[16];
#pragma unroll
  for (int ci = 0; ci < 16; ++ci) acc[ci] = 0.f;

  for (int k = 0; k < 9; ++k) {  // NOT unrolled: keeps register pressure low
    const float4v a = *(const float4v*)(&aff_s[k][l * 4]);
    const float* pblk = pfb + pbase[k] + li * KW + lj4;
#pragma unroll
    for (int ci = 0; ci < 16; ++ci) {
      const float4v x = *(const float4v*)(pblk + (size_t)ci * KN);
      acc[ci] = fmaf(x.x, a.x, fmaf(x.y, a.y, fmaf(x.z, a.z, fmaf(x.w, a.w, acc[ci]))));
    }
  }

#pragma unroll
  for (int ci = 0; ci < 16; ++ci) {
    float v = acc[ci];
#pragma unroll
    for (int off = 32; off > 0; off >>= 1) v += __shfl_down(v, off, 64);
    if (l == 0) spix1[((size_t)b * KC + w * 16 + ci) * KNS + s] = v * inv_den;
  }
}

// ---------------------------------------------------------------------------
// Kernel D: write the full dense output (B, ns, N). Plain streaming stores
// (fillBuffer reaches 6.9 TB/s with plain stores; NT was unproven).
__global__ __launch_bounds__(256) void write_out_kernel(
    const float* __restrict__ aff, float* __restrict__ out) {
  int wg = blockIdx.x;
  int s  = wg % KNS;
  int b  = wg / KNS;
  int sr = s / KNSW, sc = s % KNSW;
  int t  = threadIdx.x;

  float4v* orow = (float4v*)(out + ((size_t)b * KNS + s) * KN);
  const float* affb = aff + (size_t)b * 9 * KN;

  int it0 = blockIdx.y * 25;
#pragma unroll 5
  for (int ii = 0; ii < 25; ++ii) {
    int q = (it0 + ii) * 256 + t;  // float4 index in row
    int p = q * 4;
    unsigned r   = (unsigned)p / KW;
    unsigned col = (unsigned)p - r * KW;
    int r0 = (int)(r >> 4), c0 = (int)(col >> 4);
    int dr = sr - r0, dc = sc - c0;
    float4v v = (float4v)(0.f);
    if (dr >= -1 && dr <= 1 && dc >= -1 && dc <= 1) {
      int k = (dr + 1) * 3 + (dc + 1);
      v = *(const float4v*)(affb + (size_t)k * KN + p);
    }
    orow[q] = v;
  }
}

// ---------------------------------------------------------------------------
extern "C" void kernel_launch(void* const* d_in, const int* in_sizes, int n_in,
                              void* d_out, int out_size, void* d_ws, size_t ws_size,
                              hipStream_t stream) {
  const float* pf = (const float*)d_in[0];
  float* out = (float*)d_out;

  float* spix0 = (float*)d_ws;
  float* spix1 = spix0 + (size_t)KB * KC * KNS;
  float* affws = spix1 + (size_t)KB * KC * KNS;

  block_mean_kernel<<<KB * KC * KNSH, 320, 0, stream>>>(pf, spix0);
  dist_aff_kernel<<<KB * KNS, 256, 0, stream>>>(pf, spix0, affws);
  update_spix_kernel<<<KB * KNS, 256, 0, stream>>>(pf, affws, spix1);
  dist_aff_kernel<<<KB * KNS, 256, 0, stream>>>(pf, spix1, affws);
  dim3 gridD(KB * KNS, 4);
  write_out_kernel<<<gridD, 256, 0, stream>>>(affws, out);
}

// Round 5
// 215.153 us; speedup vs baseline: 1.2945x; 1.2945x over previous
//
#include <hip/hip_runtime.h>

// Problem constants (fixed by setup_inputs: (2, 64, 320, 320), stoken 16x16)
#define KB   2
#define KC   64
#define KH   320
#define KW   320
#define KSH  16
#define KSW  16
#define KNSH 20
#define KNSW 20
#define KNS  400           // KNSH*KNSW
#define KN   102400        // KH*KW

typedef float float4v __attribute__((ext_vector_type(4)));

// ---------------------------------------------------------------------------
// Kernel A: spix0 = per-block mean of pixel features.
__global__ __launch_bounds__(320) void block_mean_kernel(
    const float* __restrict__ pf, float* __restrict__ spix) {
  int wg = blockIdx.x;
  int rb = wg % KNSH;
  int c  = (wg / KNSH) % KC;
  int b  = wg / (KNSH * KC);
  int t  = threadIdx.x;  // 0..319

  const float* row0 = pf + ((size_t)(b * KC + c) * KH + rb * KSH) * KW;
  float acc = 0.f;
#pragma unroll
  for (int i = 0; i < KSH; ++i) acc += row0[i * KW + t];

#pragma unroll
  for (int off = 8; off > 0; off >>= 1) acc += __shfl_down(acc, off, 16);

  if ((t & 15) == 0)
    spix[(b * KC + c) * KNS + rb * KNSW + (t >> 4)] = acc * (1.0f / (KSH * KSW));
}

// ---------------------------------------------------------------------------
// Kernel B: per-pixel 9-candidate distances + masked softmax -> aff (B, 9, N).
__global__ __launch_bounds__(256) void dist_aff_kernel(
    const float* __restrict__ pf, const float* __restrict__ spix,
    float* __restrict__ aff) {
  __shared__ float scand[9][KC];

  int wg = blockIdx.x;
  int s  = wg % KNS;
  int b  = wg / KNS;
  int sr = s / KNSW, sc = s % KNSW;
  int t  = threadIdx.x;

  for (int idx = t; idx < 9 * KC; idx += 256) {
    int k = idx >> 6, c = idx & 63;
    int rr = sr + k / 3 - 1, cc = sc + k % 3 - 1;
    float v = 0.f;
    if (rr >= 0 && rr < KNSH && cc >= 0 && cc < KNSW)
      v = spix[(b * KC + c) * KNS + rr * KNSW + cc];
    scand[k][c] = v;
  }
  __syncthreads();

  int i = t >> 4, j = t & 15;
  int p = (sr * KSH + i) * KW + sc * KSW + j;
  const float* pfb = pf + (size_t)b * KC * KN + p;

  float d[9];
#pragma unroll
  for (int k = 0; k < 9; ++k) d[k] = 0.f;

  for (int c = 0; c < KC; ++c) {
    float x = pfb[(size_t)c * KN];
#pragma unroll
    for (int k = 0; k < 9; ++k) {
      float df = x - scand[k][c];
      d[k] = fmaf(df, df, d[k]);
    }
  }

  float m = 3.4e38f;
#pragma unroll
  for (int k = 0; k < 9; ++k) {
    int rr = sr + k / 3 - 1, cc = sc + k % 3 - 1;
    bool valid = (rr >= 0 && rr < KNSH && cc >= 0 && cc < KNSW);
    if (valid) m = fminf(m, d[k]);
  }
  float e[9];
  float sum = 0.f;
#pragma unroll
  for (int k = 0; k < 9; ++k) {
    int rr = sr + k / 3 - 1, cc = sc + k % 3 - 1;
    bool valid = (rr >= 0 && rr < KNSH && cc >= 0 && cc < KNSW);
    e[k] = valid ? __expf(m - d[k]) : 0.f;
    sum += e[k];
  }
  float inv = 1.0f / sum;
#pragma unroll
  for (int k = 0; k < 9; ++k)
    aff[((size_t)b * 9 + k) * KN + p] = e[k] * inv;
}

// ---------------------------------------------------------------------------
// Kernel C v4: spix1[b,c,s] = (sum_p aff*pf) / (sum_p aff + 1e-16), gather.
// One wg per (b,s), 256 threads = 4 waves; wave w owns channels 16w..16w+15.
// All-static indexing: 9 aff float4s pre-loaded into named regs (unrolled k),
// channel-blocks of 4 with NAMED accumulators; no runtime-indexed local
// arrays (rule #20), ~80 VGPR.
__global__ __launch_bounds__(256) void update_spix_kernel(
    const float* __restrict__ pf, const float* __restrict__ aff,
    float* __restrict__ spix1) {
  __shared__ __align__(16) float aff_s[9][256];
  __shared__ float red_s[4];
  __shared__ float invden_s;

  int wg = blockIdx.x;
  int s  = wg % KNS;
  int b  = wg / KNS;
  int sr = s / KNSW, sc = s % KNSW;
  int t  = threadIdx.x;

  // stage aff (invalid neighbors -> 0) and accumulate denominator
  int ti = t >> 4, tj = t & 15;
  float psum = 0.f;
#pragma unroll
  for (int k = 0; k < 9; ++k) {
    int rr = sr + k / 3 - 1, cc = sc + k % 3 - 1;
    float a = 0.f;
    if (rr >= 0 && rr < KNSH && cc >= 0 && cc < KNSW) {
      int p = (rr * KSH + ti) * KW + cc * KSW + tj;
      a = aff[((size_t)b * 9 + (8 - k)) * KN + p];
    }
    aff_s[k][t] = a;
    psum += a;
  }
#pragma unroll
  for (int off = 32; off > 0; off >>= 1) psum += __shfl_down(psum, off, 64);
  if ((t & 63) == 0) red_s[t >> 6] = psum;
  __syncthreads();
  if (t == 0) invden_s = 1.0f / (red_s[0] + red_s[1] + red_s[2] + red_s[3] + 1e-16f);
  __syncthreads();
  float inv_den = invden_s;

  int w = t >> 6, l = t & 63;
  int li = l >> 2, lj4 = (l & 3) * 4;
  const float* pfb = pf + ((size_t)b * KC + w * 16) * KN + li * KW + lj4;

  // per-k pixel-block offsets as compile-time-selected scalars (static only)
#define PBOFF(k) \
  ((min(max(sr + (k) / 3 - 1, 0), KNSH - 1) * KSH) * KW + \
    min(max(sc + (k) % 3 - 1, 0), KNSW - 1) * KSW)
  const int pb0 = PBOFF(0), pb1 = PBOFF(1), pb2 = PBOFF(2);
  const int pb3 = PBOFF(3), pb4 = PBOFF(4), pb5 = PBOFF(5);
  const int pb6 = PBOFF(6), pb7 = PBOFF(7), pb8 = PBOFF(8);
#undef PBOFF

  // all 9 aff fragments in named regs (36 VGPR, held across cb loop)
  const float4v a0 = *(const float4v*)(&aff_s[0][l * 4]);
  const float4v a1 = *(const float4v*)(&aff_s[1][l * 4]);
  const float4v a2 = *(const float4v*)(&aff_s[2][l * 4]);
  const float4v a3 = *(const float4v*)(&aff_s[3][l * 4]);
  const float4v a4 = *(const float4v*)(&aff_s[4][l * 4]);
  const float4v a5 = *(const float4v*)(&aff_s[5][l * 4]);
  const float4v a6 = *(const float4v*)(&aff_s[6][l * 4]);
  const float4v a7 = *(const float4v*)(&aff_s[7][l * 4]);
  const float4v a8 = *(const float4v*)(&aff_s[8][l * 4]);

  for (int cb = 0; cb < 4; ++cb) {  // 4 channels per pass, named accumulators
    const float* p0 = pfb + (size_t)(cb * 4 + 0) * KN;
    const float* p1 = pfb + (size_t)(cb * 4 + 1) * KN;
    const float* p2 = pfb + (size_t)(cb * 4 + 2) * KN;
    const float* p3 = pfb + (size_t)(cb * 4 + 3) * KN;
    float c0 = 0.f, c1 = 0.f, c2 = 0.f, c3 = 0.f;

#define ACCUM(pb, av)                                                    \
    {                                                                    \
      float4v x0 = *(const float4v*)(p0 + (pb));                         \
      float4v x1 = *(const float4v*)(p1 + (pb));                         \
      float4v x2 = *(const float4v*)(p2 + (pb));                         \
      float4v x3 = *(const float4v*)(p3 + (pb));                         \
      c0 = fmaf(x0.x, av.x, fmaf(x0.y, av.y, fmaf(x0.z, av.z, fmaf(x0.w, av.w, c0)))); \
      c1 = fmaf(x1.x, av.x, fmaf(x1.y, av.y, fmaf(x1.z, av.z, fmaf(x1.w, av.w, c1)))); \
      c2 = fmaf(x2.x, av.x, fmaf(x2.y, av.y, fmaf(x2.z, av.z, fmaf(x2.w, av.w, c2)))); \
      c3 = fmaf(x3.x, av.x, fmaf(x3.y, av.y, fmaf(x3.z, av.z, fmaf(x3.w, av.w, c3)))); \
    }
    ACCUM(pb0, a0) ACCUM(pb1, a1) ACCUM(pb2, a2)
    ACCUM(pb3, a3) ACCUM(pb4, a4) ACCUM(pb5, a5)
    ACCUM(pb6, a6) ACCUM(pb7, a7) ACCUM(pb8, a8)
#undef ACCUM

#pragma unroll
    for (int off = 32; off > 0; off >>= 1) {
      c0 += __shfl_down(c0, off, 64);
      c1 += __shfl_down(c1, off, 64);
      c2 += __shfl_down(c2, off, 64);
      c3 += __shfl_down(c3, off, 64);
    }
    if (l == 0) {
      float* dst = spix1 + ((size_t)b * KC + w * 16 + cb * 4) * KNS + s;
      dst[0 * KNS] = c0 * inv_den;
      dst[1 * KNS] = c1 * inv_den;
      dst[2 * KNS] = c2 * inv_den;
      dst[3 * KNS] = c3 * inv_den;
    }
  }
}

// ---------------------------------------------------------------------------
// Kernel D: write the full dense output (B, ns, N). NT stores: measured
// ~93 us faster than plain stores for this 327.7 MB stream (R3 vs R4).
__global__ __launch_bounds__(256) void write_out_kernel(
    const float* __restrict__ aff, float* __restrict__ out) {
  int wg = blockIdx.x;
  int s  = wg % KNS;
  int b  = wg / KNS;
  int sr = s / KNSW, sc = s % KNSW;
  int t  = threadIdx.x;

  float4v* orow = (float4v*)(out + ((size_t)b * KNS + s) * KN);
  const float* affb = aff + (size_t)b * 9 * KN;

  int it0 = blockIdx.y * 25;
#pragma unroll 5
  for (int ii = 0; ii < 25; ++ii) {
    int q = (it0 + ii) * 256 + t;  // float4 index in row
    int p = q * 4;
    unsigned r   = (unsigned)p / KW;
    unsigned col = (unsigned)p - r * KW;
    int r0 = (int)(r >> 4), c0 = (int)(col >> 4);
    int dr = sr - r0, dc = sc - c0;
    float4v v = (float4v)(0.f);
    if (dr >= -1 && dr <= 1 && dc >= -1 && dc <= 1) {
      int k = (dr + 1) * 3 + (dc + 1);
      v = *(const float4v*)(affb + (size_t)k * KN + p);
    }
    __builtin_nontemporal_store(v, &orow[q]);
  }
}

// ---------------------------------------------------------------------------
extern "C" void kernel_launch(void* const* d_in, const int* in_sizes, int n_in,
                              void* d_out, int out_size, void* d_ws, size_t ws_size,
                              hipStream_t stream) {
  const float* pf = (const float*)d_in[0];
  float* out = (float*)d_out;

  float* spix0 = (float*)d_ws;
  float* spix1 = spix0 + (size_t)KB * KC * KNS;
  float* affws = spix1 + (size_t)KB * KC * KNS;

  block_mean_kernel<<<KB * KC * KNSH, 320, 0, stream>>>(pf, spix0);
  dist_aff_kernel<<<KB * KNS, 256, 0, stream>>>(pf, spix0, affws);
  update_spix_kernel<<<KB * KNS, 256, 0, stream>>>(pf, affws, spix1);
  dist_aff_kernel<<<KB * KNS, 256, 0, stream>>>(pf, spix1, affws);
  dim3 gridD(KB * KNS, 4);
  write_out_kernel<<<gridD, 256, 0, stream>>>(affws, out);
}

// Round 6
// 161.873 us; speedup vs baseline: 1.7206x; 1.3291x over previous
//
#include <hip/hip_runtime.h>

// Problem constants (fixed by setup_inputs: (2, 64, 320, 320), stoken 16x16)
#define KB   2
#define KC   64
#define KH   320
#define KW   320
#define KSH  16
#define KSW  16
#define KNSH 20
#define KNSW 20
#define KNS  400           // KNSH*KNSW
#define KN   102400        // KH*KW

typedef float float4v __attribute__((ext_vector_type(4)));

// ---------------------------------------------------------------------------
// Kernel A: spix0 = per-block mean of pixel features.
__global__ __launch_bounds__(320) void block_mean_kernel(
    const float* __restrict__ pf, float* __restrict__ spix) {
  int wg = blockIdx.x;
  int rb = wg % KNSH;
  int c  = (wg / KNSH) % KC;
  int b  = wg / (KNSH * KC);
  int t  = threadIdx.x;  // 0..319

  const float* row0 = pf + ((size_t)(b * KC + c) * KH + rb * KSH) * KW;
  float acc = 0.f;
#pragma unroll
  for (int i = 0; i < KSH; ++i) acc += row0[i * KW + t];

#pragma unroll
  for (int off = 8; off > 0; off >>= 1) acc += __shfl_down(acc, off, 16);

  if ((t & 15) == 0)
    spix[(b * KC + c) * KNS + rb * KNSW + (t >> 4)] = acc * (1.0f / (KSH * KSW));
}

// ---------------------------------------------------------------------------
// Kernel B: per-pixel 9-candidate distances + masked softmax -> aff (B, 9, N).
__global__ __launch_bounds__(256) void dist_aff_kernel(
    const float* __restrict__ pf, const float* __restrict__ spix,
    float* __restrict__ aff) {
  __shared__ float scand[9][KC];

  int wg = blockIdx.x;
  int s  = wg % KNS;
  int b  = wg / KNS;
  int sr = s / KNSW, sc = s % KNSW;
  int t  = threadIdx.x;

  for (int idx = t; idx < 9 * KC; idx += 256) {
    int k = idx >> 6, c = idx & 63;
    int rr = sr + k / 3 - 1, cc = sc + k % 3 - 1;
    float v = 0.f;
    if (rr >= 0 && rr < KNSH && cc >= 0 && cc < KNSW)
      v = spix[(b * KC + c) * KNS + rr * KNSW + cc];
    scand[k][c] = v;
  }
  __syncthreads();

  int i = t >> 4, j = t & 15;
  int p = (sr * KSH + i) * KW + sc * KSW + j;
  const float* pfb = pf + (size_t)b * KC * KN + p;

  float d[9];
#pragma unroll
  for (int k = 0; k < 9; ++k) d[k] = 0.f;

  for (int c = 0; c < KC; ++c) {
    float x = pfb[(size_t)c * KN];
#pragma unroll
    for (int k = 0; k < 9; ++k) {
      float df = x - scand[k][c];
      d[k] = fmaf(df, df, d[k]);
    }
  }

  float m = 3.4e38f;
#pragma unroll
  for (int k = 0; k < 9; ++k) {
    int rr = sr + k / 3 - 1, cc = sc + k % 3 - 1;
    bool valid = (rr >= 0 && rr < KNSH && cc >= 0 && cc < KNSW);
    if (valid) m = fminf(m, d[k]);
  }
  float e[9];
  float sum = 0.f;
#pragma unroll
  for (int k = 0; k < 9; ++k) {
    int rr = sr + k / 3 - 1, cc = sc + k % 3 - 1;
    bool valid = (rr >= 0 && rr < KNSH && cc >= 0 && cc < KNSW);
    e[k] = valid ? __expf(m - d[k]) : 0.f;
    sum += e[k];
  }
  float inv = 1.0f / sum;
#pragma unroll
  for (int k = 0; k < 9; ++k)
    aff[((size_t)b * 9 + k) * KN + p] = e[k] * inv;
}

// ---------------------------------------------------------------------------
// Kernel S1: scatter partials. wg per (b, source block). Reads pf ONCE total.
// part[((b*KNS+blk)*9 + k)*64 + c] = sum_{p in blk} aff_k[p] * pf_c[p]
// den[(b*KNS+blk)*9 + k]           = sum_{p in blk} aff_k[p]
__global__ __launch_bounds__(256) void scatter_partial_kernel(
    const float* __restrict__ pf, const float* __restrict__ aff,
    float* __restrict__ part, float* __restrict__ den) {
  __shared__ __align__(16) float aff_s[9][256];
  __shared__ float part_s[9][64];
  __shared__ float den_s[9];

  int wg  = blockIdx.x;
  int blk = wg % KNS;
  int b   = wg / KNS;
  int br  = blk / KNSW, bc = blk % KNSW;
  int t   = threadIdx.x;
  int ti  = t >> 4, tj = t & 15;
  int p   = (br * KSH + ti) * KW + bc * KSW + tj;

#pragma unroll
  for (int k = 0; k < 9; ++k)
    aff_s[k][t] = aff[((size_t)b * 9 + k) * KN + p];
  __syncthreads();

  int w = t >> 6, l = t & 63;
  int li = l >> 2, lj4 = (l & 3) * 4;
  const float* pfb = pf + ((size_t)b * KC + w * 16) * KN
                   + (br * KSH + li) * KW + bc * KSW + lj4;

  const float4v a0 = *(const float4v*)(&aff_s[0][l * 4]);
  const float4v a1 = *(const float4v*)(&aff_s[1][l * 4]);
  const float4v a2 = *(const float4v*)(&aff_s[2][l * 4]);
  const float4v a3 = *(const float4v*)(&aff_s[3][l * 4]);
  const float4v a4 = *(const float4v*)(&aff_s[4][l * 4]);
  const float4v a5 = *(const float4v*)(&aff_s[5][l * 4]);
  const float4v a6 = *(const float4v*)(&aff_s[6][l * 4]);
  const float4v a7 = *(const float4v*)(&aff_s[7][l * 4]);
  const float4v a8 = *(const float4v*)(&aff_s[8][l * 4]);

  // denominators (aff is channel-independent; wave 0 does it)
  if (w == 0) {
#define DENK(k, av)                                                       \
    {                                                                     \
      float dv = (av.x + av.y) + (av.z + av.w);                           \
      _Pragma("unroll")                                                   \
      for (int off = 32; off > 0; off >>= 1) dv += __shfl_xor(dv, off, 64); \
      if (l == 0) den_s[k] = dv;                                          \
    }
    DENK(0, a0) DENK(1, a1) DENK(2, a2) DENK(3, a3) DENK(4, a4)
    DENK(5, a5) DENK(6, a6) DENK(7, a7) DENK(8, a8)
#undef DENK
  }

  // wave w owns channels [16w, 16w+16); 4 chunks of 4 channels
#pragma unroll
  for (int cb = 0; cb < 4; ++cb) {
    float4v x0 = *(const float4v*)(pfb + (size_t)(cb * 4 + 0) * KN);
    float4v x1 = *(const float4v*)(pfb + (size_t)(cb * 4 + 1) * KN);
    float4v x2 = *(const float4v*)(pfb + (size_t)(cb * 4 + 2) * KN);
    float4v x3 = *(const float4v*)(pfb + (size_t)(cb * 4 + 3) * KN);

    float acc[4][9];
#define DOTS(c, xv)                                                        \
    acc[c][0] = fmaf(xv.x, a0.x, fmaf(xv.y, a0.y, fmaf(xv.z, a0.z, xv.w * a0.w))); \
    acc[c][1] = fmaf(xv.x, a1.x, fmaf(xv.y, a1.y, fmaf(xv.z, a1.z, xv.w * a1.w))); \
    acc[c][2] = fmaf(xv.x, a2.x, fmaf(xv.y, a2.y, fmaf(xv.z, a2.z, xv.w * a2.w))); \
    acc[c][3] = fmaf(xv.x, a3.x, fmaf(xv.y, a3.y, fmaf(xv.z, a3.z, xv.w * a3.w))); \
    acc[c][4] = fmaf(xv.x, a4.x, fmaf(xv.y, a4.y, fmaf(xv.z, a4.z, xv.w * a4.w))); \
    acc[c][5] = fmaf(xv.x, a5.x, fmaf(xv.y, a5.y, fmaf(xv.z, a5.z, xv.w * a5.w))); \
    acc[c][6] = fmaf(xv.x, a6.x, fmaf(xv.y, a6.y, fmaf(xv.z, a6.z, xv.w * a6.w))); \
    acc[c][7] = fmaf(xv.x, a7.x, fmaf(xv.y, a7.y, fmaf(xv.z, a7.z, xv.w * a7.w))); \
    acc[c][8] = fmaf(xv.x, a8.x, fmaf(xv.y, a8.y, fmaf(xv.z, a8.z, xv.w * a8.w)));
    DOTS(0, x0) DOTS(1, x1) DOTS(2, x2) DOTS(3, x3)
#undef DOTS

#pragma unroll
    for (int off = 32; off > 0; off >>= 1)
#pragma unroll
      for (int c = 0; c < 4; ++c)
#pragma unroll
        for (int k = 0; k < 9; ++k)
          acc[c][k] += __shfl_xor(acc[c][k], off, 64);

    if (l == 0) {
#pragma unroll
      for (int c = 0; c < 4; ++c)
#pragma unroll
        for (int k = 0; k < 9; ++k)
          part_s[k][w * 16 + cb * 4 + c] = acc[c][k];
    }
  }
  __syncthreads();

  size_t base = ((size_t)b * KNS + blk) * 9;
  for (int idx = t; idx < 9 * 64; idx += 256)
    part[base * 64 + idx] = part_s[idx >> 6][idx & 63];
  if (t < 9) den[base + t] = den_s[t];
}

// ---------------------------------------------------------------------------
// Kernel S2: combine 9 neighbor partials -> spix1[b][c][s]. Wave per s.
__global__ __launch_bounds__(256) void reduce_spix_kernel(
    const float* __restrict__ part, const float* __restrict__ den,
    float* __restrict__ spix1) {
  int w = threadIdx.x >> 6, c = threadIdx.x & 63;
  int sid = blockIdx.x * 4 + w;          // grid = KB*KNS/4
  int s = sid % KNS;
  int b = sid / KNS;
  int sr = s / KNSW, sc = s % KNSW;

  float num = 0.f, dsum = 0.f;
#pragma unroll
  for (int j = 0; j < 9; ++j) {
    int rr = sr + j / 3 - 1, cc = sc + j % 3 - 1;
    if (rr >= 0 && rr < KNSH && cc >= 0 && cc < KNSW) {
      size_t base = ((size_t)b * KNS + rr * KNSW + cc) * 9 + (8 - j);
      num  += part[base * 64 + c];
      dsum += den[base];
    }
  }
  spix1[((size_t)b * KC + c) * KNS + s] = num / (dsum + 1e-16f);
}

// ---------------------------------------------------------------------------
// Kernel D2: sparse valid-region writer. Bulk zeroing is done by
// hipMemsetAsync (proven 6.9 TB/s fillBuffer path); this writes only the
// <=48x48 valid rect per output row (7.4 MB total), NT to skip L2.
__global__ __launch_bounds__(256) void sparse_out_kernel(
    const float* __restrict__ aff, float* __restrict__ out) {
  int wg = blockIdx.x;
  int s  = wg % KNS;
  int b  = wg / KNS;
  int sr = s / KNSW, sc = s % KNSW;
  int t  = threadIdx.x;

  float* orow = out + ((size_t)b * KNS + s) * KN;
  const float* affb = aff + (size_t)b * 9 * KN;

  int rbase  = (sr - 1) * KSH;   // virtual 48-row x 12-float4 rect anchor
  int c4base = (sc - 1) * 4;

#pragma unroll
  for (int ii = 0; ii < 3; ++ii) {
    int idx = ii * 256 + t;      // 0..575 (48*12)
    if (idx >= 576) break;
    int vr = idx / 12, vc = idx - vr * 12;
    int r  = rbase + vr;
    int c4 = c4base + vc;
    if (r < 0 || r >= KH || c4 < 0 || c4 >= KW / 4) continue;
    // plane k s.t. pixel's candidate k == s:  k = 8 - 3*(vr/16) - (vc/4)
    int k = 8 - (vr >> 4) * 3 - (vc >> 2);
    int p = r * KW + c4 * 4;
    float4v v = *(const float4v*)(affb + (size_t)k * KN + p);
    __builtin_nontemporal_store(v, (float4v*)(orow + p));
  }
}

// ---------------------------------------------------------------------------
extern "C" void kernel_launch(void* const* d_in, const int* in_sizes, int n_in,
                              void* d_out, int out_size, void* d_ws, size_t ws_size,
                              hipStream_t stream) {
  const float* pf = (const float*)d_in[0];
  float* out = (float*)d_out;

  // ws (floats): spix0 [51200] | spix1 [51200] | aff [1843200] |
  //              part [460800] | den [7200]
  float* spix0 = (float*)d_ws;
  float* spix1 = spix0 + (size_t)KB * KC * KNS;
  float* affws = spix1 + (size_t)KB * KC * KNS;
  float* partw = affws + (size_t)KB * 9 * KN;
  float* denw  = partw + (size_t)KB * KNS * 9 * 64;

  block_mean_kernel<<<KB * KC * KNSH, 320, 0, stream>>>(pf, spix0);
  dist_aff_kernel<<<KB * KNS, 256, 0, stream>>>(pf, spix0, affws);
  scatter_partial_kernel<<<KB * KNS, 256, 0, stream>>>(pf, affws, partw, denw);
  reduce_spix_kernel<<<KB * KNS / 4, 256, 0, stream>>>(partw, denw, spix1);
  dist_aff_kernel<<<KB * KNS, 256, 0, stream>>>(pf, spix1, affws);
  hipMemsetAsync(d_out, 0, (size_t)out_size * sizeof(float), stream);
  sparse_out_kernel<<<KB * KNS, 256, 0, stream>>>(affws, out);
}